// Round 9
// baseline (250.946 us; speedup 1.0000x reference)
//
#include <hip/hip_runtime.h>
#include <hip/hip_cooperative_groups.h>

namespace cg = cooperative_groups;

// Problem constants
#define NB 64
#define NL 128
#define NQ 128
#define NE 16384

// ws float layout
#define WS_W     0         // [i][j] row-major fp32 W
#define WS_TW    16384     // total weight
#define WS_PART  16385     // 256 per-block numerator partials (ends 16641)
// ws ushort layout (bf16 operand arrays), offsets in ushorts from ws base
#define US_ATB   33288                   // [q][p] A_fid^T bf16 (byte 66576, 16B aligned)
#define US_PB    (US_ATB + 16384)        // [b][i][k] P bf16 plain
#define US_PTB   (US_PB + NB * 16384)    // [b][q][j] P bf16 transposed

#define SMEM_FLOATS 8448                 // 33792 B: fits T[128][132] ushort / Wl[64][128] f32

using short8 = __attribute__((ext_vector_type(8))) short;  // 8 bf16
using f32x4  = __attribute__((ext_vector_type(4))) float;

// fp32 -> bf16 bits, round-to-nearest-even
__device__ inline unsigned short f2bf(float f) {
    const unsigned u = __float_as_uint(f);
    return (unsigned short)((u + 0x7fffu + ((u >> 16) & 1u)) >> 16);
}

__device__ inline short8 pack8(float4 a, float4 b) {
    short8 r;
    r[0] = f2bf(a.x); r[1] = f2bf(a.y); r[2] = f2bf(a.z); r[3] = f2bf(a.w);
    r[4] = f2bf(b.x); r[5] = f2bf(b.y); r[6] = f2bf(b.z); r[7] = f2bf(b.w);
    return r;
}

// ---------------------------------------------------------------------------
// Phase A (98 active blocks x 512 threads):
//  blk 0-63 : PB (bf16 plain) + PTB (bf16 transposed via LDS tile) for b=blk
//  blk 64-95: ATB[q][p] bf16
//  blk 96-97: W edge-scatter, half'd by i-row (64 rows = 32 KB LDS each);
//             blk 96 also reduces total weight.
// ---------------------------------------------------------------------------
__device__ inline void phaseA_dev(int blk, int t,
                                  const float* __restrict__ P,
                                  const float* __restrict__ dhw,
                                  const float* __restrict__ derr,
                                  const int* __restrict__ pairs,
                                  const float* __restrict__ wts,
                                  float* __restrict__ ws, float* smem) {
    unsigned short* us = (unsigned short*)ws;
    if (blk < 64) {
        const float* __restrict__ Pb = P + blk * 16384;
        unsigned short* __restrict__ PBb  = us + US_PB  + blk * 16384;
        unsigned short* __restrict__ PTBb = us + US_PTB + blk * 16384;
        unsigned short* T = (unsigned short*)smem;     // [128][132]

        #pragma unroll
        for (int r = 0; r < 8; ++r) {
            const int f = t + 512 * r;                 // float4 idx [0,4096)
            const float4 v = ((const float4*)Pb)[f];
            ushort4 u;
            u.x = f2bf(v.x); u.y = f2bf(v.y); u.z = f2bf(v.z); u.w = f2bf(v.w);
            ((ushort4*)PBb)[f] = u;
            const int i = f >> 5, c = (f & 31) * 4;
            *(ushort4*)&T[i * 132 + c] = u;
        }
        __syncthreads();
        #pragma unroll
        for (int r = 0; r < 4; ++r) {
            const int o  = t + 512 * r;                // short8 idx [0,2048)
            const int q  = o & 127;
            const int j0 = (o >> 7) * 8;
            short8 rd;
            #pragma unroll
            for (int d = 0; d < 8; ++d)
                rd[d] = (short)T[(j0 + d) * 132 + q];
            *(short8*)&PTBb[q * 128 + j0] = rd;
        }
    } else if (blk < 96) {
        const int idx = (blk - 64) * 512 + t;          // [0, 16384)
        const float hw = dhw[idx];
        const float er = derr[idx];
        const float a  = (hw == 1.0f) ? fmaxf(1.0f - er, 0.f) : 0.f;
        const int p = idx >> 7, q = idx & 127;
        us[US_ATB + q * 128 + p] = f2bf(a);
    } else if (blk < 98) {
        const int half = blk - 96;                     // i-rows [half*64, half*64+64)
        float* Wl = smem;                              // 8192 floats = 32 KB
        #pragma unroll
        for (int r = 0; r < 4; ++r)
            ((float4*)Wl)[t + 512 * r] = make_float4(0.f, 0.f, 0.f, 0.f);
        __syncthreads();

        float tw = 0.f;
        #pragma unroll 4
        for (int r = 0; r < 32; ++r) {
            const int e = t + 512 * r;                 // [0, 16384)
            const int2  pr = ((const int2*)pairs)[e];
            const float w  = wts[e];
            tw += w;
            if ((pr.x >> 6) == half)
                atomicAdd(&Wl[(pr.x & 63) * 128 + pr.y], w);
        }
        __syncthreads();
        #pragma unroll
        for (int r = 0; r < 4; ++r)
            ((float4*)&ws[WS_W + half * 8192])[t + 512 * r] =
                ((const float4*)Wl)[t + 512 * r];

        if (half == 0) {
            __syncthreads();                           // Wl copy done; reuse slots
            #pragma unroll
            for (int off = 32; off; off >>= 1) tw += __shfl_down(tw, off, 64);
            if ((t & 63) == 0) smem[t >> 6] = tw;
            __syncthreads();
            if (t == 0) {
                float s = 0.f;
                #pragma unroll
                for (int k = 0; k < 8; ++k) s += smem[k];
                ws[WS_TW] = s;
            }
        }
    }
}

// ---------------------------------------------------------------------------
// Phase B (256 blocks x 512 threads, 2 units each): unit u = (b, 16-row
// i-tile); 8 waves = 8 q-tiles. accG = W*P_b frag, accY = P_b*A frag,
// s += <accG,accY>. Block-reduce -> WS_PART[blk].
// ---------------------------------------------------------------------------
__device__ inline void phaseB_dev(int blk, int t,
                                  const float* __restrict__ wsc,
                                  float* __restrict__ ws, float* smem) {
    const unsigned short* us = (const unsigned short*)wsc;
    const unsigned short* __restrict__ ATB = us + US_ATB;
    const int wv   = t >> 6;
    const int lane = t & 63;
    const int kb   = (lane >> 4) * 8;

    float s = 0.f;
    #pragma unroll
    for (int uu = 0; uu < 2; ++uu) {
        const int u  = blk * 2 + uu;                   // [0, 512)
        const int b  = u >> 3;
        const int i0 = (u & 7) * 16;
        const unsigned short* __restrict__ PBb  = us + US_PB  + b * 16384;
        const unsigned short* __restrict__ PTBb = us + US_PTB + b * 16384;
        const int mrow = i0 + (lane & 15);
        const int ncol = wv * 16 + (lane & 15);
        const float* __restrict__ Wrow = wsc + WS_W + mrow * 128;

        f32x4 accG = {0.f, 0.f, 0.f, 0.f};
        f32x4 accY = {0.f, 0.f, 0.f, 0.f};
        #pragma unroll
        for (int kk = 0; kk < 4; ++kk) {
            const int k0 = kk * 32 + kb;
            const short8 wa = pack8(*(const float4*)&Wrow[k0],
                                    *(const float4*)&Wrow[k0 + 4]);
            const short8 gb = *(const short8*)&PTBb[ncol * 128 + k0];
            const short8 pa = *(const short8*)&PBb[mrow * 128 + k0];
            const short8 yb = *(const short8*)&ATB[ncol * 128 + k0];
            accG = __builtin_amdgcn_mfma_f32_16x16x32_bf16(wa, gb, accG, 0, 0, 0);
            accY = __builtin_amdgcn_mfma_f32_16x16x32_bf16(pa, yb, accY, 0, 0, 0);
        }
        s += accG[0] * accY[0] + accG[1] * accY[1]
           + accG[2] * accY[2] + accG[3] * accY[3];
    }

    #pragma unroll
    for (int off = 32; off; off >>= 1) s += __shfl_down(s, off, 64);
    if (lane == 0) smem[wv] = s;
    __syncthreads();
    if (t == 0) {
        float acc = 0.f;
        #pragma unroll
        for (int k = 0; k < 8; ++k) acc += smem[k];
        ws[WS_PART + blk] = acc;
    }
}

// ---------------------------------------------------------------------------
// Phase C: reduce 256 partials, write loss.
// ---------------------------------------------------------------------------
__device__ inline void phaseC_dev(int t, const float* __restrict__ ws,
                                  float* __restrict__ out, float* smem) {
    const int lane = t & 63, wv = t >> 6;
    float n = (t < 256) ? ws[WS_PART + t] : 0.f;
    #pragma unroll
    for (int off = 32; off; off >>= 1) n += __shfl_down(n, off, 64);
    if (lane == 0) smem[wv] = n;
    __syncthreads();
    if (t == 0) {
        float num = 0.f;
        #pragma unroll
        for (int k = 0; k < 8; ++k) num += smem[k];
        out[0] = -num / ((float)NB * fmaxf(ws[WS_TW], 1e-8f));
    }
}

// ---------------------------------------------------------------------------
// Fused cooperative kernel: 256 blocks x 512 threads, 33.8 KB LDS.
// ---------------------------------------------------------------------------
__global__ __launch_bounds__(512) void fused_kernel(const float* __restrict__ P,
                                                    const float* __restrict__ dhw,
                                                    const float* __restrict__ derr,
                                                    const int* __restrict__ pairs,
                                                    const float* __restrict__ wts,
                                                    float* __restrict__ ws,
                                                    float* __restrict__ out) {
    __shared__ float smem[SMEM_FLOATS];
    const int t = threadIdx.x, blk = blockIdx.x;

    phaseA_dev(blk, t, P, dhw, derr, pairs, wts, ws, smem);
    __threadfence();
    cg::this_grid().sync();
    __threadfence();

    phaseB_dev(blk, t, ws, ws, smem);
    __threadfence();
    cg::this_grid().sync();
    __threadfence();

    if (blk == 0) {
        __syncthreads();
        phaseC_dev(t, ws, out, smem);
    }
}

// --------------------- fallback: separate dispatches -----------------------
__global__ __launch_bounds__(512) void kA(const float* __restrict__ P,
                                          const float* __restrict__ dhw,
                                          const float* __restrict__ derr,
                                          const int* __restrict__ pairs,
                                          const float* __restrict__ wts,
                                          float* __restrict__ ws) {
    __shared__ float smem[SMEM_FLOATS];
    phaseA_dev(blockIdx.x, threadIdx.x, P, dhw, derr, pairs, wts, ws, smem);
}
__global__ __launch_bounds__(512) void kB(float* __restrict__ ws) {
    __shared__ float smem[16];
    phaseB_dev(blockIdx.x, threadIdx.x, ws, ws, smem);
}
__global__ __launch_bounds__(512) void kC(const float* __restrict__ ws,
                                          float* __restrict__ out) {
    __shared__ float smem[16];
    phaseC_dev(threadIdx.x, ws, out, smem);
}

extern "C" void kernel_launch(void* const* d_in, const int* in_sizes, int n_in,
                              void* d_out, int out_size, void* d_ws, size_t ws_size,
                              hipStream_t stream) {
    const float* P    = (const float*)d_in[0];
    const float* dhw  = (const float*)d_in[1];
    const float* derr = (const float*)d_in[2];
    const int*   prs  = (const int*)d_in[3];
    const float* wts  = (const float*)d_in[4];
    float* ws  = (float*)d_ws;
    float* out = (float*)d_out;

    void* args[] = {(void*)&P, (void*)&dhw, (void*)&derr, (void*)&prs,
                    (void*)&wts, (void*)&ws, (void*)&out};
    hipError_t err = hipLaunchCooperativeKernel((void*)fused_kernel, dim3(256),
                                                dim3(512), args, 0, stream);
    if (err != hipSuccess) {
        // Fallback: same phases as separate dispatches (round-7 structure).
        kA<<<98, 512, 0, stream>>>(P, dhw, derr, prs, wts, ws);
        kB<<<256, 512, 0, stream>>>(ws);
        kC<<<1, 512, 0, stream>>>(ws, out);
    }
}

// Round 10
// 33.858 us; speedup vs baseline: 7.4118x; 7.4118x over previous
//
#include <hip/hip_runtime.h>

// Problem constants
#define NB 64
#define NL 128
#define NQ 128
#define NE 16384

// ws float layout
#define WS_W     0         // [i][j] row-major fp32 W
#define WS_TW    16384     // total weight
#define WS_NUM   16385     // numerator accumulator (zeroed by prep)
#define WS_CNT   16386     // int ticket counter (zeroed by prep)
// ws ushort layout (bf16 operand arrays), offsets in ushorts from ws base
#define US_ATB   32784                   // [q][p] A_fid^T bf16 (byte 65568, 16B aligned)
#define US_PB    (US_ATB + 16384)        // [b][i][k] P bf16 plain
#define US_PTB   (US_PB + NB * 16384)    // [b][q][j] P bf16 transposed

using short8 = __attribute__((ext_vector_type(8))) short;  // 8 bf16
using f32x4  = __attribute__((ext_vector_type(4))) float;

// fp32 -> bf16 bits, round-to-nearest-even
__device__ inline unsigned short f2bf(float f) {
    const unsigned u = __float_as_uint(f);
    return (unsigned short)((u + 0x7fffu + ((u >> 16) & 1u)) >> 16);
}

__device__ inline short8 pack8(float4 a, float4 b) {
    short8 r;
    r[0] = f2bf(a.x); r[1] = f2bf(a.y); r[2] = f2bf(a.z); r[3] = f2bf(a.w);
    r[4] = f2bf(b.x); r[5] = f2bf(b.y); r[6] = f2bf(b.z); r[7] = f2bf(b.w);
    return r;
}

// ---------------------------------------------------------------------------
// prep: 98 blocks x 512 threads.
//  blk 0-63 : PB (bf16 plain) + PTB (bf16 transposed via LDS tile) for b=blk
//  blk 64-95: ATB[q][p] bf16
//  blk 96-97: W edge-scatter by i-row half via LDS (32 KB each) -> overwrite
//             W rows (kills the memset dispatch). blk 96 also writes TW and
//             zeroes NUM/CNT for the batch kernel's ticket finalize.
// ---------------------------------------------------------------------------
__global__ __launch_bounds__(512) void prep_kernel(const float* __restrict__ P,
                                                   const float* __restrict__ dhw,
                                                   const float* __restrict__ derr,
                                                   const int* __restrict__ pairs,
                                                   const float* __restrict__ wts,
                                                   float* __restrict__ ws) {
    __shared__ float smem[8448];          // 33.8 KB union
    const int t = threadIdx.x, blk = blockIdx.x;
    unsigned short* us = (unsigned short*)ws;

    if (blk < 64) {
        const float* __restrict__ Pb = P + blk * 16384;
        unsigned short* __restrict__ PBb  = us + US_PB  + blk * 16384;
        unsigned short* __restrict__ PTBb = us + US_PTB + blk * 16384;
        unsigned short* T = (unsigned short*)smem;     // [128][132]

        #pragma unroll
        for (int r = 0; r < 8; ++r) {
            const int f = t + 512 * r;                 // float4 idx [0,4096)
            const float4 v = ((const float4*)Pb)[f];
            ushort4 u;
            u.x = f2bf(v.x); u.y = f2bf(v.y); u.z = f2bf(v.z); u.w = f2bf(v.w);
            ((ushort4*)PBb)[f] = u;                    // coalesced 8B stores
            const int i = f >> 5, c = (f & 31) * 4;
            *(ushort4*)&T[i * 132 + c] = u;
        }
        __syncthreads();
        #pragma unroll
        for (int r = 0; r < 4; ++r) {
            const int o  = t + 512 * r;                // short8 idx [0,2048)
            const int q  = o & 127;
            const int j0 = (o >> 7) * 8;
            short8 rd;
            #pragma unroll
            for (int d = 0; d < 8; ++d)
                rd[d] = (short)T[(j0 + d) * 132 + q];
            *(short8*)&PTBb[q * 128 + j0] = rd;
        }
    } else if (blk < 96) {
        const int idx = (blk - 64) * 512 + t;          // [0, 16384)
        const float hw = dhw[idx];
        const float er = derr[idx];
        const float a  = (hw == 1.0f) ? fmaxf(1.0f - er, 0.f) : 0.f;
        const int p = idx >> 7, q = idx & 127;
        us[US_ATB + q * 128 + p] = f2bf(a);
    } else {
        const int half = blk - 96;                     // i-rows [half*64, half*64+64)
        float* Wl = smem;                              // 8192 floats = 32 KB
        #pragma unroll
        for (int r = 0; r < 4; ++r)
            ((float4*)Wl)[t + 512 * r] = make_float4(0.f, 0.f, 0.f, 0.f);
        __syncthreads();

        float tw = 0.f;
        #pragma unroll 4
        for (int r = 0; r < 32; ++r) {
            const int e = t + 512 * r;                 // [0, 16384)
            const int2  pr = ((const int2*)pairs)[e];
            const float w  = wts[e];
            tw += w;
            if ((pr.x >> 6) == half)
                atomicAdd(&Wl[(pr.x & 63) * 128 + pr.y], w);  // LDS, distributed
        }
        __syncthreads();
        #pragma unroll
        for (int r = 0; r < 4; ++r)
            ((float4*)&ws[WS_W + half * 8192])[t + 512 * r] =
                ((const float4*)Wl)[t + 512 * r];      // overwrite: no memset

        if (half == 0) {
            __syncthreads();                           // Wl copy issued; reuse smem
            #pragma unroll
            for (int off = 32; off; off >>= 1) tw += __shfl_down(tw, off, 64);
            if ((t & 63) == 0) smem[t >> 6] = tw;
            __syncthreads();
            if (t == 0) {
                float s = 0.f;
                #pragma unroll
                for (int k = 0; k < 8; ++k) s += smem[k];
                ws[WS_TW]  = s;
                ws[WS_NUM] = 0.f;
                ((int*)ws)[WS_CNT] = 0;
            }
        }
    }
}

// ---------------------------------------------------------------------------
// batch + fused finalize: 256 blocks x 512 threads, 2 units each.
// unit u = (b, 16-row i-tile); 8 waves = 8 q-tiles.
//   accG = sum mfma(Wfrag, PTfrag)  -> G = W * P_b
//   accY = sum mfma(Pfrag, ATfrag)  -> Y = P_b * A
//   s += <accG, accY>  (C-layout invariant)
// Block acc -> atomicAdd into NUM; ticket; last block writes the loss.
// ---------------------------------------------------------------------------
__global__ __launch_bounds__(512) void batch_kernel(float* __restrict__ ws,
                                                    float* __restrict__ out) {
    __shared__ float smem[8];
    const int t = threadIdx.x, blk = blockIdx.x;
    const unsigned short* us = (const unsigned short*)ws;
    const unsigned short* __restrict__ ATB = us + US_ATB;
    const int wv   = t >> 6;
    const int lane = t & 63;
    const int kb   = (lane >> 4) * 8;

    float s = 0.f;
    #pragma unroll
    for (int uu = 0; uu < 2; ++uu) {
        const int u  = blk * 2 + uu;                   // [0, 512)
        const int b  = u >> 3;
        const int i0 = (u & 7) * 16;
        const unsigned short* __restrict__ PBb  = us + US_PB  + b * 16384;
        const unsigned short* __restrict__ PTBb = us + US_PTB + b * 16384;
        const int mrow = i0 + (lane & 15);
        const int ncol = wv * 16 + (lane & 15);
        const float* __restrict__ Wrow = ws + WS_W + mrow * 128;

        f32x4 accG = {0.f, 0.f, 0.f, 0.f};
        f32x4 accY = {0.f, 0.f, 0.f, 0.f};
        #pragma unroll
        for (int kk = 0; kk < 4; ++kk) {
            const int k0 = kk * 32 + kb;
            const short8 wa = pack8(*(const float4*)&Wrow[k0],
                                    *(const float4*)&Wrow[k0 + 4]);
            const short8 gb = *(const short8*)&PTBb[ncol * 128 + k0];
            const short8 pa = *(const short8*)&PBb[mrow * 128 + k0];
            const short8 yb = *(const short8*)&ATB[ncol * 128 + k0];
            accG = __builtin_amdgcn_mfma_f32_16x16x32_bf16(wa, gb, accG, 0, 0, 0);
            accY = __builtin_amdgcn_mfma_f32_16x16x32_bf16(pa, yb, accY, 0, 0, 0);
        }
        s += accG[0] * accY[0] + accG[1] * accY[1]
           + accG[2] * accY[2] + accG[3] * accY[3];
    }

    #pragma unroll
    for (int off = 32; off; off >>= 1) s += __shfl_down(s, off, 64);
    if (lane == 0) smem[wv] = s;
    __syncthreads();
    if (t == 0) {
        float acc = 0.f;
        #pragma unroll
        for (int k = 0; k < 8; ++k) acc += smem[k];
        atomicAdd(&ws[WS_NUM], acc);                   // device-scope
        __threadfence();
        const int old = atomicAdd((int*)ws + WS_CNT, 1);
        if (old == 255) {                              // last block finalizes
            const float num = atomicAdd(&ws[WS_NUM], 0.0f);   // coherent read
            const float tw  = fmaxf(ws[WS_TW], 1e-8f);
            out[0] = -num / ((float)NB * tw);
        }
    }
}

extern "C" void kernel_launch(void* const* d_in, const int* in_sizes, int n_in,
                              void* d_out, int out_size, void* d_ws, size_t ws_size,
                              hipStream_t stream) {
    const float* P    = (const float*)d_in[0];
    const float* dhw  = (const float*)d_in[1];
    const float* derr = (const float*)d_in[2];
    const int*   prs  = (const int*)d_in[3];
    const float* wts  = (const float*)d_in[4];
    float* ws  = (float*)d_ws;
    float* out = (float*)d_out;

    prep_kernel<<<98, 512, 0, stream>>>(P, dhw, derr, prs, wts, ws);
    batch_kernel<<<256, 512, 0, stream>>>(ws, out);
}

// Round 11
// 24.727 us; speedup vs baseline: 10.1489x; 1.3693x over previous
//
#include <hip/hip_runtime.h>

// Problem constants
#define NB 64
#define NL 128
#define NQ 128
#define NE 16384

// ws float layout
#define WS_TW    0         // total weight (written by block 0)
#define WS_PART  8         // 256 per-block numerator partials (16B-aligned)

using short8 = __attribute__((ext_vector_type(8))) short;  // 8 bf16
using f32x4  = __attribute__((ext_vector_type(4))) float;

// fp32 -> bf16 bits, round-to-nearest-even
__device__ inline unsigned short f2bf(float f) {
    const unsigned u = __float_as_uint(f);
    return (unsigned short)((u + 0x7fffu + ((u >> 16) & 1u)) >> 16);
}

// ---------------------------------------------------------------------------
// main: 256 blocks x 512 threads, fully block-local (no inter-block deps).
// block = (b = blk>>2, i-stripe qtr = blk&3 -> rows [qtr*32, qtr*32+32)).
//  1. load full P_b -> regs -> LDS bf16 [128][136] (pad: conflict-free rows+cols)
//  2. zero W LDS [32][132]; scan ALL edges: tw += w; scatter own-stripe edges
//     via LDS atomicAdd (distributed addresses)
//  3. hoist B-frags: gb from P_b LDS columns; yb from dhw/derr on the fly
//  4. per i-tile (2): wa from W LDS, pa from P_b LDS rows; 8 MFMA; s += <G,Y>
//  5. block-reduce (s, tw) -> WS_PART[blk]; blk 0 writes TW.
// ---------------------------------------------------------------------------
__global__ __launch_bounds__(512) void main_kernel(const float* __restrict__ P,
                                                   const float* __restrict__ dhw,
                                                   const float* __restrict__ derr,
                                                   const int*  __restrict__ pairs,
                                                   const float* __restrict__ wts,
                                                   float* __restrict__ ws) {
    __shared__ float Wl[32 * 132];             // 16896 B fp32 scatter target
    __shared__ unsigned short Pbl[128 * 136];  // 34816 B bf16 P_b (padded)
    __shared__ float redS[8], redT[8];

    const int t   = threadIdx.x;
    const int blk = blockIdx.x;                // [0,256)
    const int b   = blk >> 2;
    const int qtr = blk & 3;                   // i-rows [qtr*32, qtr*32+32)
    const float* __restrict__ Pb = P + b * 16384;

    // 1a. issue full P_b load early (latency hides under W zero + edge scan)
    float4 pv[8];
    #pragma unroll
    for (int r = 0; r < 8; ++r) pv[r] = ((const float4*)Pb)[t + 512 * r];

    // 2a. zero Wl (4224 floats)
    #pragma unroll
    for (int r = 0; r < 9; ++r) {
        const int idx = t + 512 * r;
        if (idx < 32 * 132) Wl[idx] = 0.f;
    }
    __syncthreads();

    // 1b. write P_b to LDS as bf16, padded stride 136
    #pragma unroll
    for (int r = 0; r < 8; ++r) {
        const int f   = t + 512 * r;           // ushort4 unit within [128][128]
        const int row = f >> 5, c4 = (f & 31) * 4;
        ushort4 u;
        u.x = f2bf(pv[r].x); u.y = f2bf(pv[r].y);
        u.z = f2bf(pv[r].z); u.w = f2bf(pv[r].w);
        *(ushort4*)&Pbl[row * 136 + c4] = u;
    }

    // 2b. edge scan: total weight + own-stripe LDS scatter
    float tw = 0.f;
    #pragma unroll 4
    for (int r = 0; r < 32; ++r) {
        const int e    = t + 512 * r;          // [0, 16384)
        const int2  pr = ((const int2*)pairs)[e];
        const float w  = wts[e];
        tw += w;
        if ((pr.x >> 5) == qtr)
            atomicAdd(&Wl[(pr.x & 31) * 132 + pr.y], w);
    }
    __syncthreads();

    // 3. hoisted unit-independent B-operand fragments
    const int wv   = t >> 6;                   // wave -> q-tile
    const int lane = t & 63;
    const int l15  = lane & 15;
    const int kb   = (lane >> 4) * 8;
    const int ncol = wv * 16 + l15;

    short8 gb8[4], yb8[4];
    #pragma unroll
    for (int kk = 0; kk < 4; ++kk) {
        const int k0 = kk * 32 + kb;
        short8 g, y;
        #pragma unroll
        for (int d = 0; d < 8; ++d) {
            g[d] = (short)Pbl[(k0 + d) * 136 + ncol];          // P_b[j][ncol]
            const int ai   = (k0 + d) * 128 + ncol;            // A[p][q] idx
            const float hw = dhw[ai], er = derr[ai];
            y[d] = (short)f2bf((hw == 1.0f) ? fmaxf(1.0f - er, 0.f) : 0.f);
        }
        gb8[kk] = g; yb8[kk] = y;
    }

    // 4. two i-tiles: accG = W*P_b frag, accY = P_b*A frag, s += <accG,accY>
    float s = 0.f;
    #pragma unroll
    for (int uu = 0; uu < 2; ++uu) {
        const int lrow = uu * 16 + l15;        // row within Wl stripe
        const int mrow = qtr * 32 + lrow;      // global i row
        f32x4 accG = {0.f, 0.f, 0.f, 0.f};
        f32x4 accY = {0.f, 0.f, 0.f, 0.f};
        #pragma unroll
        for (int kk = 0; kk < 4; ++kk) {
            const int k0 = kk * 32 + kb;
            const float4 w0 = *(const float4*)&Wl[lrow * 132 + k0];
            const float4 w1 = *(const float4*)&Wl[lrow * 132 + k0 + 4];
            short8 wa;
            wa[0] = f2bf(w0.x); wa[1] = f2bf(w0.y);
            wa[2] = f2bf(w0.z); wa[3] = f2bf(w0.w);
            wa[4] = f2bf(w1.x); wa[5] = f2bf(w1.y);
            wa[6] = f2bf(w1.z); wa[7] = f2bf(w1.w);
            const short8 pa = *(const short8*)&Pbl[mrow * 136 + k0];
            accG = __builtin_amdgcn_mfma_f32_16x16x32_bf16(wa, gb8[kk], accG, 0, 0, 0);
            accY = __builtin_amdgcn_mfma_f32_16x16x32_bf16(pa, yb8[kk], accY, 0, 0, 0);
        }
        s += accG[0] * accY[0] + accG[1] * accY[1]
           + accG[2] * accY[2] + accG[3] * accY[3];
    }

    // 5. dual block-reduce (s, tw); one plain store per block
    #pragma unroll
    for (int off = 32; off; off >>= 1) {
        s  += __shfl_down(s,  off, 64);
        tw += __shfl_down(tw, off, 64);
    }
    if (lane == 0) { redS[wv] = s; redT[wv] = tw; }
    __syncthreads();
    if (t == 0) {
        float ss = 0.f, tt = 0.f;
        #pragma unroll
        for (int k = 0; k < 8; ++k) { ss += redS[k]; tt += redT[k]; }
        ws[WS_PART + blk] = ss;                // distinct slot
        if (blk == 0) ws[WS_TW] = tt;          // full-scan value, any block equal
    }
}

// ---------------------------------------------------------------------------
// finalize: 1 block x 256 threads; loss = -(sum(part)/B)/max(tw,1e-8)
// ---------------------------------------------------------------------------
__global__ __launch_bounds__(256) void finalize_kernel(const float* __restrict__ ws,
                                                       float* __restrict__ out) {
    const int t = threadIdx.x, lane = t & 63, wv = t >> 6;
    float n = ws[WS_PART + t];
    #pragma unroll
    for (int off = 32; off; off >>= 1) n += __shfl_down(n, off, 64);
    __shared__ float red[4];
    if (lane == 0) red[wv] = n;
    __syncthreads();
    if (t == 0) {
        const float num = red[0] + red[1] + red[2] + red[3];
        out[0] = -num / ((float)NB * fmaxf(ws[WS_TW], 1e-8f));
    }
}

extern "C" void kernel_launch(void* const* d_in, const int* in_sizes, int n_in,
                              void* d_out, int out_size, void* d_ws, size_t ws_size,
                              hipStream_t stream) {
    const float* P    = (const float*)d_in[0];
    const float* dhw  = (const float*)d_in[1];
    const float* derr = (const float*)d_in[2];
    const int*   prs  = (const int*)d_in[3];
    const float* wts  = (const float*)d_in[4];
    float* ws  = (float*)d_ws;
    float* out = (float*)d_out;

    main_kernel<<<256, 512, 0, stream>>>(P, dhw, derr, prs, wts, ws);
    finalize_kernel<<<1, 256, 0, stream>>>(ws, out);
}